// Round 4
// baseline (479.554 us; speedup 1.0000x reference)
//
#include <hip/hip_runtime.h>

#define TT    2000
#define NG    4000
#define WARM  365
#define LENF  15
#define NPHY  12
#define BLK   15                  // timesteps per staged block
#define SLOTW 64                  // dwords per step in LDS (48 used + 16 pad)
#define SLOTD (BLK * SLOTW)       // 960 dwords per block slot
#define NBLK  134                 // 134*15 = 2010 steps (covers TT, stores gated)

typedef const float __attribute__((address_space(1)))* gptr_t;
typedef float __attribute__((address_space(3)))* lptr_t;

// One workgroup = one wave = 16 grid cells (4 multiplier lanes each).
// x_phy staged through a 4-slot LDS ring via global_load_lds with counted
// vmcnt waits (never drain to 0): block b+2's loads are in flight while
// block b computes -> HBM latency hidden under ~2000 cyc of chain compute.
__global__ __launch_bounds__(64, 1) void hbv_route_kernel(
    const float* __restrict__ xphy,   // [T, G, 3]
    const float* __restrict__ prm,    // [1, G, 50]
    float* __restrict__ out)          // [T-WARM, G]
{
    __shared__ float lds[4 * SLOTD];  // 15360 B

    const int lane = threadIdx.x;     // 0..63
    const int g0   = blockIdx.x * 16; // 250 blocks * 16 g = 4000
    const int g    = g0 + (lane >> 2);
    const int m    = lane & 3;

    const float* pg = prm + (size_t)g * (NPHY * 4 + 2);

    const float lb[NPHY] = {1.0f, 50.0f, 0.05f, 0.01f, 0.001f, 0.2f, 0.0f, 0.0f, -2.5f, 0.5f, 0.0f, 0.0f};
    const float ub[NPHY] = {6.0f, 1000.0f, 0.9f, 0.5f, 0.2f, 1.0f, 10.0f, 100.0f, 2.5f, 10.0f, 0.1f, 0.2f};
    float ph[NPHY];
    #pragma unroll
    for (int i = 0; i < NPHY; ++i)
        ph[i] = lb[i] + pg[i * 4 + m] * (ub[i] - lb[i]);

    const float beta = ph[0], fc = ph[1], k0 = ph[2], k1 = ph[3], k2 = ph[4],
                lp = ph[5], perc = ph[6], uzl = ph[7], ttp = ph[8],
                cfmax = ph[9], cfr = ph[10], cwh = ph[11];
    const float rfc   = 1.0f / fc;
    const float rlpfc = 1.0f / (lp * fc);
    const float cfrcf = cfr * cfmax;

    // Routing weights (gammaln / th^aa cancel under normalization).
    const float aa  = fmaxf(pg[48] * 2.9f, 0.0f) + 0.1f;
    const float th  = fmaxf(pg[49] * 6.5f, 0.0f) + 0.5f;
    const float rth = 1.0f / th;
    const float LOG2E = 1.4426950408889634f;
    float w[LENF];
    float wsum = 0.0f;
    #pragma unroll
    for (int k = 0; k < LENF; ++k) {
        const float tg = (float)k + 0.5f;
        const float e = (aa - 1.0f) * __builtin_log2f(tg) - tg * rth * LOG2E;
        w[k] = __builtin_amdgcn_exp2f(e);
        wsum += w[k];
    }
    const float rw = 1.0f / wsum;
    #pragma unroll
    for (int k = 0; k < LENF; ++k) w[k] *= rw;

    float snowpack = 0.001f, meltwater = 0.001f, sm = 0.001f, suz = 0.001f, slz = 0.001f;

    float acc[LENF];
    #pragma unroll
    for (int k = 0; k < LENF; ++k) acc[k] = 0.0f;

    const bool writer = (m == 0);
    // per-lane global dword offset within a step's 48-dword panel (clamped pad lanes)
    const int loffd = (lane < 48 ? lane : 47);

    auto issue_blk = [&](int b) {
        const int slot = b & 3;
        const int t0 = b * BLK;
        #pragma unroll
        for (int c = 0; c < BLK; ++c) {
            int t = t0 + c;
            if (t > TT - 1) t = TT - 1;
            const float* gsrc = xphy + (size_t)t * (3 * NG) + g0 * 3 + loffd;
            float* ldst = &lds[slot * SLOTD + c * SLOTW];
            __builtin_amdgcn_global_load_lds((gptr_t)gsrc, (lptr_t)ldst, 4, 0, 0);
        }
    };

    auto compute_blk = [&](int b) {
        const int slot = b & 3;
        const int t0 = b * BLK;
        const float* lbase = &lds[slot * SLOTD + (lane >> 2) * 3];
        #pragma unroll
        for (int j = 0; j < BLK; ++j) {
            const int t = t0 + j;
            const float Pt   = lbase[j * SLOTW + 0];
            const float Tm   = lbase[j * SLOTW + 1];
            const float PETt = lbase[j * SLOTW + 2];

            // off-chain precompute
            const float dT      = Tm - ttp;
            const float meltcap = fmaxf(cfmax * dT, 0.0f);
            const float refcap  = fmaxf(-cfrcf * dT, 0.0f);
            const float rain    = (Tm >= ttp) ? Pt : 0.0f;
            const float snow    = Pt - rain;
            const float sw = fminf(__builtin_amdgcn_exp2f(beta * __builtin_amdgcn_logf(sm * rfc)), 1.0f);

            // snow chain
            snowpack += snow;
            const float melt = fminf(meltcap, snowpack);
            meltwater += melt;
            snowpack  -= melt;
            const float refreeze = fminf(refcap, meltwater);
            snowpack  += refreeze;
            meltwater -= refreeze;
            const float tosoil = fmaxf(meltwater - cwh * snowpack, 0.0f);
            meltwater -= tosoil;

            // soil chain
            const float rt       = rain + tosoil;
            const float recharge = rt * sw;
            sm = sm + rt - recharge;
            const float excess = fmaxf(sm - fc, 0.0f);
            sm -= excess;
            const float evap  = fminf(sm * rlpfc, 1.0f);
            const float etact = fminf(sm, PETt * evap);
            sm = fmaxf(sm - etact, 1e-5f);

            // response chain
            suz = suz + recharge + excess;
            const float prc = fminf(suz, perc);
            suz -= prc;
            const float q0 = k0 * fmaxf(suz - uzl, 0.0f);
            suz -= q0;
            const float q1 = k1 * suz;
            suz -= q1;
            slz += prc;
            const float q2 = k2 * slz;
            slz -= q2;
            float q = q0 + q1 + q2;

            // mean over the 4 multipliers (quad-local)
            q += __shfl_xor(q, 1);
            q += __shfl_xor(q, 2);
            q *= 0.25f;

            // fused 15-tap causal conv, scatter form; ring head == j (static)
            const float o = acc[j] + w[0] * q;
            acc[j] = 0.0f;
            #pragma unroll
            for (int k = 1; k < LENF; ++k) {
                int idx = j + k;
                if (idx >= LENF) idx -= LENF;
                acc[idx] += w[k] * q;
            }

            if (writer && t >= WARM && t < TT)
                out[(size_t)(t - WARM) * NG + g] = o;
        }
    };

    // Pipeline: 2 blocks staged ahead; steady-state wait leaves the newest
    // loads in flight (never vmcnt(0) in the loop).
    issue_blk(0);
    issue_blk(1);
    for (int b = 0; b < NBLK; ++b) {
        asm volatile("s_waitcnt vmcnt(15)" ::: "memory");  // block b landed
        issue_blk(b + 2);                                  // t-clamped past end
        compute_blk(b);
    }
}

extern "C" void kernel_launch(void* const* d_in, const int* in_sizes, int n_in,
                              void* d_out, int out_size, void* d_ws, size_t ws_size,
                              hipStream_t stream) {
    const float* xphy = (const float*)d_in[0];   // [2000, 4000, 3]
    const float* prm  = (const float*)d_in[1];   // [1, 4000, 50]
    float* out = (float*)d_out;                  // [1635, 4000, 1]

    hbv_route_kernel<<<NG / 16, 64, 0, stream>>>(xphy, prm, out);
}

// Round 5
// 312.740 us; speedup vs baseline: 1.5334x; 1.5334x over previous
//
#include <hip/hip_runtime.h>

#define TT    2000
#define NG    4000
#define WARM  365
#define LENF  15
#define NPHY  12
#define BLK   15                  // timesteps per staged block
#define SLOTW 64                  // dwords per step in LDS (48 used + 16 pad)
#define SLOTD (BLK * SLOTW)       // 960 dwords per block slot
#define NBLK  134                 // 134*15 = 2010 steps (covers TT, stores gated)

typedef const float __attribute__((address_space(1)))* gptr_t;
typedef float __attribute__((address_space(3)))* lptr_t;

// Quad-wide sum via DPP (VALU-only; no LDS pipe, no lgkmcnt).
// 0xB1 = quad_perm(1,0,3,2), 0x4E = quad_perm(2,3,0,1).
__device__ __forceinline__ float quad_sum(float x) {
    int a = __builtin_amdgcn_update_dpp(0, __float_as_int(x), 0xB1, 0xF, 0xF, true);
    float s = x + __int_as_float(a);
    int b = __builtin_amdgcn_update_dpp(0, __float_as_int(s), 0x4E, 0xF, 0xF, true);
    return s + __int_as_float(b);
}

// One workgroup = one wave = 16 grid cells (4 multiplier lanes each).
// x_phy staged via global_load_lds into a 4-slot LDS ring (counted vmcnt wait,
// never drained to 0); each block's 45 values are pulled into registers right
// after the wait so no ds_read sits on the per-step dependency chain.
__global__ __launch_bounds__(64, 1) void hbv_route_kernel(
    const float* __restrict__ xphy,   // [T, G, 3]
    const float* __restrict__ prm,    // [1, G, 50]
    float* __restrict__ out)          // [T-WARM, G]
{
    __shared__ float lds[4 * SLOTD];  // 15360 B

    const int lane = threadIdx.x;     // 0..63
    const int g0   = blockIdx.x * 16; // 250 blocks * 16 g = 4000
    const int g    = g0 + (lane >> 2);
    const int m    = lane & 3;

    const float* pg = prm + (size_t)g * (NPHY * 4 + 2);

    const float lb[NPHY] = {1.0f, 50.0f, 0.05f, 0.01f, 0.001f, 0.2f, 0.0f, 0.0f, -2.5f, 0.5f, 0.0f, 0.0f};
    const float ub[NPHY] = {6.0f, 1000.0f, 0.9f, 0.5f, 0.2f, 1.0f, 10.0f, 100.0f, 2.5f, 10.0f, 0.1f, 0.2f};
    float ph[NPHY];
    #pragma unroll
    for (int i = 0; i < NPHY; ++i)
        ph[i] = lb[i] + pg[i * 4 + m] * (ub[i] - lb[i]);

    const float beta = ph[0], fc = ph[1], k0 = ph[2], k1 = ph[3], k2 = ph[4],
                lp = ph[5], perc = ph[6], uzl = ph[7], ttp = ph[8],
                cfmax = ph[9], cfr = ph[10], cwh = ph[11];
    const float rfc   = 1.0f / fc;
    const float rlpfc = 1.0f / (lp * fc);
    const float cfrcf = cfr * cfmax;

    // Routing weights (gammaln / th^aa cancel under normalization).
    const float aa  = fmaxf(pg[48] * 2.9f, 0.0f) + 0.1f;
    const float th  = fmaxf(pg[49] * 6.5f, 0.0f) + 0.5f;
    const float rth = 1.0f / th;
    const float LOG2E = 1.4426950408889634f;
    float w[LENF];
    float wsum = 0.0f;
    #pragma unroll
    for (int k = 0; k < LENF; ++k) {
        const float tg = (float)k + 0.5f;
        const float e = (aa - 1.0f) * __builtin_log2f(tg) - tg * rth * LOG2E;
        w[k] = __builtin_amdgcn_exp2f(e);
        wsum += w[k];
    }
    const float rw = 1.0f / wsum;
    #pragma unroll
    for (int k = 0; k < LENF; ++k) w[k] *= rw;

    float snowpack = 0.001f, meltwater = 0.001f, sm = 0.001f, suz = 0.001f, slz = 0.001f;

    float acc[LENF];
    #pragma unroll
    for (int k = 0; k < LENF; ++k) acc[k] = 0.0f;

    // per-lane global dword offset within a step's 48-dword panel (pad lanes clamp)
    const int loffd = (lane < 48 ? lane : 47);

    auto issue_blk = [&](int b) {
        const int slot = b & 3;
        const int t0 = b * BLK;
        #pragma unroll
        for (int c = 0; c < BLK; ++c) {
            int t = t0 + c;
            if (t > TT - 1) t = TT - 1;
            const float* gsrc = xphy + (size_t)t * (3 * NG) + g0 * 3 + loffd;
            float* ldst = &lds[slot * SLOTD + c * SLOTW];
            __builtin_amdgcn_global_load_lds((gptr_t)gsrc, (lptr_t)ldst, 4, 0, 0);
        }
    };

    // Pipeline: 2 blocks staged ahead; counted waits never drain the queue.
    issue_blk(0);
    issue_blk(1);

    for (int b = 0; b < NBLK; ++b) {
        asm volatile("s_waitcnt vmcnt(15)" ::: "memory");  // block b's data resident
        issue_blk(b + 2);                                  // t-clamped past end

        const int t0 = b * BLK;
        const float* lbase = &lds[(b & 3) * SLOTD + (lane >> 2) * 3];

        // Pull the whole block into registers (static indices -> VGPRs);
        // 45 independent ds_reads, latency amortized once per block.
        float Pv[BLK], Tv[BLK], Ev[BLK];
        #pragma unroll
        for (int j = 0; j < BLK; ++j) {
            Pv[j] = lbase[j * SLOTW + 0];
            Tv[j] = lbase[j * SLOTW + 1];
            Ev[j] = lbase[j * SLOTW + 2];
        }

        float o0 = 0.0f, o1 = 0.0f, o2 = 0.0f, o3 = 0.0f;

        #pragma unroll
        for (int j = 0; j < BLK; ++j) {
            const float Pt   = Pv[j];
            const float Tm   = Tv[j];
            const float PETt = Ev[j];

            // off-chain precompute
            const float dT      = Tm - ttp;
            const float meltcap = fmaxf(cfmax * dT, 0.0f);
            const float refcap  = fmaxf(-cfrcf * dT, 0.0f);
            const float rain    = (Tm >= ttp) ? Pt : 0.0f;
            const float snow    = Pt - rain;
            const float sw = fminf(__builtin_amdgcn_exp2f(beta * __builtin_amdgcn_logf(sm * rfc)), 1.0f);

            // snow chain
            snowpack += snow;
            const float melt = fminf(meltcap, snowpack);
            meltwater += melt;
            snowpack  -= melt;
            const float refreeze = fminf(refcap, meltwater);
            snowpack  += refreeze;
            meltwater -= refreeze;
            const float tosoil = fmaxf(meltwater - cwh * snowpack, 0.0f);
            meltwater -= tosoil;

            // soil chain
            const float rt       = rain + tosoil;
            const float recharge = rt * sw;
            sm = sm + rt - recharge;
            const float excess = fmaxf(sm - fc, 0.0f);
            sm -= excess;
            const float evap  = fminf(sm * rlpfc, 1.0f);
            const float etact = fminf(sm, PETt * evap);
            sm = fmaxf(sm - etact, 1e-5f);

            // response chain
            suz = suz + recharge + excess;
            const float prc = fminf(suz, perc);
            suz -= prc;
            const float q0 = k0 * fmaxf(suz - uzl, 0.0f);
            suz -= q0;
            const float q1 = k1 * suz;
            suz -= q1;
            slz += prc;
            const float q2 = k2 * slz;
            slz -= q2;

            // mean over the 4 multipliers: DPP quad reduction (VALU-only)
            const float q = quad_sum(q0 + q1 + q2) * 0.25f;

            // fused 15-tap causal conv, scatter form; ring head == j (static)
            const float o = acc[j] + w[0] * q;
            acc[j] = 0.0f;
            #pragma unroll
            for (int k = 1; k < LENF; ++k) {
                int idx = j + k;
                if (idx >= LENF) idx -= LENF;
                acc[idx] += w[k] * q;
            }

            // stash o into the register slot this lane will store (j%4 == m)
            const bool sel = ((j & 3) == m);
            if ((j >> 2) == 0)      o0 = sel ? o : o0;
            else if ((j >> 2) == 1) o1 = sel ? o : o1;
            else if ((j >> 2) == 2) o2 = sel ? o : o2;
            else                    o3 = sel ? o : o3;
        }

        // 4 batched stores: lane m writes steps j = 4k + m of this block.
        #pragma unroll
        for (int k = 0; k < 4; ++k) {
            const int j = k * 4 + m;
            const int t = t0 + j;
            const float ov = (k == 0) ? o0 : (k == 1) ? o1 : (k == 2) ? o2 : o3;
            if (j < BLK && t >= WARM && t < TT)
                out[(size_t)(t - WARM) * NG + g] = ov;
        }
    }
}

extern "C" void kernel_launch(void* const* d_in, const int* in_sizes, int n_in,
                              void* d_out, int out_size, void* d_ws, size_t ws_size,
                              hipStream_t stream) {
    const float* xphy = (const float*)d_in[0];   // [2000, 4000, 3]
    const float* prm  = (const float*)d_in[1];   // [1, 4000, 50]
    float* out = (float*)d_out;                  // [1635, 4000, 1]

    hbv_route_kernel<<<NG / 16, 64, 0, stream>>>(xphy, prm, out);
}

// Round 6
// 299.338 us; speedup vs baseline: 1.6020x; 1.0448x over previous
//
#include <hip/hip_runtime.h>

#define TT    2000
#define NG    4000
#define WARM  365
#define LENF  15
#define NPHY  12
#define BLK   15                  // timesteps per staged block
#define SLOTW 64                  // dwords per step in LDS (48 used + 16 pad)
#define SLOTD (BLK * SLOTW)       // 960 dwords per block slot
#define NBLK  134                 // 134*15 = 2010 steps (covers TT, stores gated)

typedef const float __attribute__((address_space(1)))* gptr_t;
typedef float __attribute__((address_space(3)))* lptr_t;

// Quad-wide sum via DPP (VALU-only; no LDS pipe).
__device__ __forceinline__ float quad_sum(float x) {
    int a = __builtin_amdgcn_update_dpp(0, __float_as_int(x), 0xB1, 0xF, 0xF, true);
    float s = x + __int_as_float(a);
    int b = __builtin_amdgcn_update_dpp(0, __float_as_int(s), 0x4E, 0xF, 0xF, true);
    return s + __int_as_float(b);
}

// One workgroup = one wave = 16 grid cells (4 multiplier lanes each).
// Stage-major 15-step blocks: snow recurrence for all 15 steps, then soil,
// then response+conv — three independent instruction pools per block so the
// scheduler hides each chain's dependency stalls under the other stages.
__global__ __launch_bounds__(64, 1) void hbv_route_kernel(
    const float* __restrict__ xphy,   // [T, G, 3]
    const float* __restrict__ prm,    // [1, G, 50]
    float* __restrict__ out)          // [T-WARM, G]
{
    __shared__ float lds[4 * SLOTD];  // 15360 B

    const int lane = threadIdx.x;     // 0..63
    const int g0   = blockIdx.x * 16; // 250 blocks * 16 g = 4000
    const int g    = g0 + (lane >> 2);
    const int m    = lane & 3;

    const float* pg = prm + (size_t)g * (NPHY * 4 + 2);

    const float lb[NPHY] = {1.0f, 50.0f, 0.05f, 0.01f, 0.001f, 0.2f, 0.0f, 0.0f, -2.5f, 0.5f, 0.0f, 0.0f};
    const float ub[NPHY] = {6.0f, 1000.0f, 0.9f, 0.5f, 0.2f, 1.0f, 10.0f, 100.0f, 2.5f, 10.0f, 0.1f, 0.2f};
    float ph[NPHY];
    #pragma unroll
    for (int i = 0; i < NPHY; ++i)
        ph[i] = lb[i] + pg[i * 4 + m] * (ub[i] - lb[i]);

    const float beta = ph[0], fc = ph[1], k0 = ph[2], k1 = ph[3], k2 = ph[4],
                lp = ph[5], perc = ph[6], uzl = ph[7], ttp = ph[8],
                cfmax = ph[9], cfr = ph[10], cwh = ph[11];
    const float rfc   = 1.0f / fc;
    const float rlpfc = 1.0f / (lp * fc);
    const float cfrcf = cfr * cfmax;

    // Routing weights (gammaln / th^aa cancel under normalization).
    // 0.25 (mean over NMUL) folded into w.
    const float aa  = fmaxf(pg[48] * 2.9f, 0.0f) + 0.1f;
    const float th  = fmaxf(pg[49] * 6.5f, 0.0f) + 0.5f;
    const float rth = 1.0f / th;
    const float LOG2E = 1.4426950408889634f;
    float w[LENF];
    float wsum = 0.0f;
    #pragma unroll
    for (int k = 0; k < LENF; ++k) {
        const float tg = (float)k + 0.5f;
        const float e = (aa - 1.0f) * __builtin_log2f(tg) - tg * rth * LOG2E;
        w[k] = __builtin_amdgcn_exp2f(e);
        wsum += w[k];
    }
    const float rw = 0.25f / wsum;
    #pragma unroll
    for (int k = 0; k < LENF; ++k) w[k] *= rw;

    float snowpack = 0.001f, meltwater = 0.001f, sm = 0.001f, suz = 0.001f, slz = 0.001f;

    float acc[LENF];
    #pragma unroll
    for (int k = 0; k < LENF; ++k) acc[k] = 0.0f;

    const int loffd = (lane < 48 ? lane : 47);

    auto issue_blk = [&](int b) {
        const int slot = b & 3;
        const int t0 = b * BLK;
        #pragma unroll
        for (int c = 0; c < BLK; ++c) {
            int t = t0 + c;
            if (t > TT - 1) t = TT - 1;
            const float* gsrc = xphy + (size_t)t * (3 * NG) + g0 * 3 + loffd;
            float* ldst = &lds[slot * SLOTD + c * SLOTW];
            __builtin_amdgcn_global_load_lds((gptr_t)gsrc, (lptr_t)ldst, 4, 0, 0);
        }
    };

    issue_blk(0);
    issue_blk(1);

    for (int b = 0; b < NBLK; ++b) {
        asm volatile("s_waitcnt vmcnt(15)" ::: "memory");  // block b resident
        issue_blk(b + 2);

        const int t0 = b * BLK;
        const float* lbase = &lds[(b & 3) * SLOTD + (lane >> 2) * 3];

        // Hoist block data into registers (static indices -> VGPRs).
        float Pv[BLK], Tv[BLK], Ev[BLK];
        #pragma unroll
        for (int j = 0; j < BLK; ++j) {
            Pv[j] = lbase[j * SLOTW + 0];
            Tv[j] = lbase[j * SLOTW + 1];
            Ev[j] = lbase[j * SLOTW + 2];
        }

        // ---- Stage 1: snow recurrence + input-only precompute ----
        float rt[BLK], uu[BLK];
        #pragma unroll
        for (int j = 0; j < BLK; ++j) {
            const float dT      = Tv[j] - ttp;
            const float rain    = (Tv[j] >= ttp) ? Pv[j] : 0.0f;
            const float snow    = Pv[j] - rain;
            const float meltcap = cfmax * fmaxf(dT, 0.0f);
            const float refcap  = cfrcf * fmaxf(-dT, 0.0f);

            snowpack += snow;
            const float melt = fminf(meltcap, snowpack);
            meltwater += melt;
            snowpack  -= melt;
            const float refreeze = fminf(refcap, meltwater);
            meltwater -= refreeze;
            snowpack  += refreeze;
            const float tosoil = fmaxf(fmaf(-cwh, snowpack, meltwater), 0.0f);
            meltwater -= tosoil;

            rt[j] = rain + tosoil;
            uu[j] = fminf(Ev[j] * rlpfc, 1.0f);   // min(PET/(lp*fc),1)
        }

        // ---- Stage 2: soil-moisture recurrence (10-op chain, 2 trans) ----
        float rex[BLK];
        #pragma unroll
        for (int j = 0; j < BLK; ++j) {
            // sw = (sm/fc)^beta; sm<=fc invariant makes the clip redundant
            const float sw    = __builtin_amdgcn_exp2f(beta * __builtin_amdgcn_logf(sm * rfc));
            const float smprt = sm + rt[j];
            const float sm1   = fmaf(-rt[j], sw, smprt);     // sm + rt*(1-sw)
            const float sm2   = fminf(sm1, fc);
            const float etact = fminf(sm2 * uu[j], Ev[j]);   // min(sm2, sm2*PET*rlpfc, PET)
            sm = fmaxf(sm2 - etact, 1e-5f);
            rex[j] = fmaf(rt[j], sw, sm1 - sm2);             // recharge + excess
        }

        // ---- Stage 3: response recurrence + quad mean + conv + store ----
        float o0 = 0.0f, o1 = 0.0f, o2 = 0.0f, o3 = 0.0f;
        #pragma unroll
        for (int j = 0; j < BLK; ++j) {
            const float suz1 = suz + rex[j];
            const float prc  = fminf(suz1, perc);
            const float suzA = suz1 - prc;
            const float tq   = fmaxf(suzA - uzl, 0.0f);
            const float q0   = k0 * tq;
            const float suzB = suzA - q0;
            const float q1   = k1 * suzB;
            suz = suzB - q1;
            const float slz1 = slz + prc;
            const float q2   = k2 * slz1;
            slz = slz1 - q2;

            const float q = quad_sum(q0 + q1 + q2);  // *0.25 folded into w

            const float o = acc[j] + w[0] * q;
            acc[j] = 0.0f;
            #pragma unroll
            for (int k = 1; k < LENF; ++k) {
                int idx = j + k;
                if (idx >= LENF) idx -= LENF;
                acc[idx] += w[k] * q;
            }

            const bool sel = ((j & 3) == m);
            if ((j >> 2) == 0)      o0 = sel ? o : o0;
            else if ((j >> 2) == 1) o1 = sel ? o : o1;
            else if ((j >> 2) == 2) o2 = sel ? o : o2;
            else                    o3 = sel ? o : o3;
        }

        // 4 batched stores: lane m writes steps j = 4k + m of this block.
        #pragma unroll
        for (int k = 0; k < 4; ++k) {
            const int j = k * 4 + m;
            const int t = t0 + j;
            const float ov = (k == 0) ? o0 : (k == 1) ? o1 : (k == 2) ? o2 : o3;
            if (j < BLK && t >= WARM && t < TT)
                out[(size_t)(t - WARM) * NG + g] = ov;
        }
    }
}

extern "C" void kernel_launch(void* const* d_in, const int* in_sizes, int n_in,
                              void* d_out, int out_size, void* d_ws, size_t ws_size,
                              hipStream_t stream) {
    const float* xphy = (const float*)d_in[0];   // [2000, 4000, 3]
    const float* prm  = (const float*)d_in[1];   // [1, 4000, 50]
    float* out = (float*)d_out;                  // [1635, 4000, 1]

    hbv_route_kernel<<<NG / 16, 64, 0, stream>>>(xphy, prm, out);
}